// Round 6
// baseline (373.184 us; speedup 1.0000x reference)
//
#include <hip/hip_runtime.h>

#define NCH 64      // channels
#define KOFF 27     // kernel offsets
#define EPSV 1e-5f
#define DSLOT 4     // pipeline depth (k-slots in flight)

typedef __attribute__((ext_vector_type(8))) short  bf16x8;
typedef __attribute__((ext_vector_type(4))) float  f32x4;
typedef __attribute__((ext_vector_type(8))) unsigned short u16x8;

__device__ __forceinline__ unsigned short f2bf(float x) {
    unsigned int u = __float_as_uint(x);
    u += 0x7fffu + ((u >> 16) & 1u);       // round-to-nearest-even
    return (unsigned short)(u >> 16);
}

// ---------------------------------------------------------------------------
// Fused prep: zero stats | W1->Wt1 | W2->Wt2 (B-fragment order) | feats->bf16
// Wt[(((k*2+s)*4+ct)*64+lane)*8 + j] = W[k][s*32+(lane>>4)*8+j][ct*16+(lane&15)]
// ---------------------------------------------------------------------------
__global__ __launch_bounds__(256)
void prep_kernel(const float* __restrict__ feats,
                 const float* __restrict__ W1, const float* __restrict__ W2,
                 unsigned short* __restrict__ fbf,
                 unsigned short* __restrict__ wt1, unsigned short* __restrict__ wt2,
                 float* __restrict__ stat, int total8)
{
    const int b = blockIdx.x;
    if (b == 0) {
        stat[threadIdx.x] = 0.f;           // 256 floats: stats1+stats2
        return;
    }
    if (b <= 108) {
        const float* W = (b <= 54) ? W1 : W2;
        unsigned short* Wt = (b <= 54) ? wt1 : wt2;
        const int t = (b <= 54 ? b - 1 : b - 55) * 256 + threadIdx.x; // 0..13823
        const int l  = t & 63;
        const int ct = (t >> 6) & 3;
        const int s  = (t >> 8) & 1;
        const int k  = t >> 9;
        const int d     = ct * 16 + (l & 15);
        const int cbase = s * 32 + (l >> 4) * 8;
        u16x8 o;
#pragma unroll
        for (int j = 0; j < 8; ++j)
            o[j] = f2bf(W[(size_t)k * 4096 + (size_t)(cbase + j) * 64 + d]);
        reinterpret_cast<u16x8*>(Wt)[t] = o;
        return;
    }
    const int idx = (b - 109) * 256 + threadIdx.x;
    if (idx >= total8) return;
    const float4* xp = reinterpret_cast<const float4*>(feats) + (size_t)idx * 2;
    const float4 a = xp[0], c = xp[1];
    u16x8 o;
    o[0] = f2bf(a.x); o[1] = f2bf(a.y); o[2] = f2bf(a.z); o[3] = f2bf(a.w);
    o[4] = f2bf(c.x); o[5] = f2bf(c.y); o[6] = f2bf(c.z); o[7] = f2bf(c.w);
    reinterpret_cast<u16x8*>(fbf)[idx] = o;
}

// ---------------------------------------------------------------------------
// Gathered conv via MFMA 16x16x32 bf16, 1 wave/block, 64 voxels x 64 ch.
// 4-deep global_load_lds pipeline (A gathered w/ XOR chunk swizzle, B
// contiguous), manual s_waitcnt vmcnt(48) discipline, fully unrolled k-loop,
// zero barriers. Fused per-channel stats via end-of-block atomics.
// ---------------------------------------------------------------------------
__global__ __launch_bounds__(64, 2)
void conv_mfma_kernel(const unsigned short* __restrict__ fin,
                      const int* __restrict__ nbr,
                      const unsigned short* __restrict__ Wt,
                      const float* __restrict__ bias,
                      float* __restrict__ out, float* __restrict__ stat, int N)
{
    __shared__ __align__(16) unsigned short sA[DSLOT * 4096];  // 4 x 8 KB
    __shared__ __align__(16) unsigned short sB[DSLOT * 4096];  // 4 x 8 KB
    __shared__ int s_idx[KOFF * 64];   // [k][row] byte offsets into fin

    const int lane = threadIdx.x;      // 0..63
    const int n0   = blockIdx.x * 64;
    const int m    = lane & 15;
    const int quad = lane >> 4;
    const int rsel = lane >> 3;        // row-within-8-group for staging
    const int vchunk = (((lane & 7) ^ (rsel & 7)) << 4);  // XOR swizzle, bytes

    {   // fill s_idx transposed ([k][row]) and pre-scaled to byte offsets
        const int rem  = N - n0;
        const int maxi = (rem < 64 ? rem : 64) * KOFF;
        const int* nb  = nbr + (size_t)n0 * KOFF;
#pragma unroll
        for (int j = 0; j < KOFF; ++j) {
            const int p   = j * 64 + lane;          // global-layout index
            const int row = p / KOFF;
            const int kk  = p - row * KOFF;
            s_idx[kk * 64 + row] = ((p < maxi) ? nb[p] : 0) * (NCH * 2);
        }
        // single wave: LDS ops complete in order, no barrier needed
    }

    const char* fbfB = (const char*)fin;
    const char* WtB  = (const char*)Wt;

    // fragment read offsets within an A slot: row v=mt*16+m, chunk c=quad+4s,
    // physical chunk p = c ^ (v&7)  (v&7 == m&7)
    int offA[4][2];
#pragma unroll
    for (int mt = 0; mt < 4; ++mt)
#pragma unroll
        for (int sf = 0; sf < 2; ++sf)
            offA[mt][sf] = (mt * 16 + m) * 128 + (((quad + 4 * sf) ^ (m & 7)) << 4);
    const int offBbase = lane * 16;

    f32x4 acc[4][4];
#pragma unroll
    for (int mt = 0; mt < 4; ++mt)
#pragma unroll
        for (int ct = 0; ct < 4; ++ct) acc[mt][ct] = (f32x4){0.f, 0.f, 0.f, 0.f};

#define STAGE(kk)                                                             \
    {                                                                         \
        const int slot_ = (kk) & (DSLOT - 1);                                 \
        _Pragma("unroll")                                                     \
        for (int i_ = 0; i_ < 8; ++i_) {                                      \
            const int ofs_ = s_idx[(kk) * 64 + i_ * 8 + rsel];                \
            __builtin_amdgcn_global_load_lds(                                 \
                (const __attribute__((address_space(1))) void*)               \
                    (fbfB + (unsigned)(ofs_ + vchunk)),                       \
                (__attribute__((address_space(3))) void*)                     \
                    ((char*)sA + slot_ * 8192 + i_ * 1024),                   \
                16, 0, 0);                                                    \
        }                                                                     \
        _Pragma("unroll")                                                     \
        for (int i_ = 0; i_ < 8; ++i_) {                                      \
            __builtin_amdgcn_global_load_lds(                                 \
                (const __attribute__((address_space(1))) void*)               \
                    (WtB + (kk) * 8192 + i_ * 1024 + offBbase),               \
                (__attribute__((address_space(3))) void*)                     \
                    ((char*)sB + slot_ * 8192 + i_ * 1024),                   \
                16, 0, 0);                                                    \
        }                                                                     \
    }

#define STEP(kk, vm)                                                          \
    {                                                                         \
        asm volatile("s_waitcnt vmcnt(%0)" :: "i"(vm) : "memory");            \
        const int slot_ = (kk) & (DSLOT - 1);                                 \
        bf16x8 Af[4][2], Bf[2][4];                                            \
        _Pragma("unroll")                                                     \
        for (int mt = 0; mt < 4; ++mt)                                        \
            _Pragma("unroll")                                                 \
            for (int sf = 0; sf < 2; ++sf)                                    \
                Af[mt][sf] = *reinterpret_cast<const bf16x8*>(                \
                    (const char*)sA + slot_ * 8192 + offA[mt][sf]);           \
        _Pragma("unroll")                                                     \
        for (int sf = 0; sf < 2; ++sf)                                        \
            _Pragma("unroll")                                                 \
            for (int ct = 0; ct < 4; ++ct)                                    \
                Bf[sf][ct] = *reinterpret_cast<const bf16x8*>(                \
                    (const char*)sB + slot_ * 8192 + (sf * 4 + ct) * 1024 +   \
                    offBbase);                                                \
        asm volatile("s_waitcnt lgkmcnt(0)" ::: "memory");                    \
        if ((kk) + DSLOT < KOFF) STAGE((kk) + DSLOT)                          \
        _Pragma("unroll")                                                     \
        for (int mt = 0; mt < 4; ++mt)                                        \
            _Pragma("unroll")                                                 \
            for (int sf = 0; sf < 2; ++sf)                                    \
                _Pragma("unroll")                                             \
                for (int ct = 0; ct < 4; ++ct)                                \
                    acc[mt][ct] = __builtin_amdgcn_mfma_f32_16x16x32_bf16(    \
                        Af[mt][sf], Bf[sf][ct], acc[mt][ct], 0, 0, 0);        \
    }

    STAGE(0) STAGE(1) STAGE(2) STAGE(3)
    STEP(0, 48)  STEP(1, 48)  STEP(2, 48)  STEP(3, 48)  STEP(4, 48)
    STEP(5, 48)  STEP(6, 48)  STEP(7, 48)  STEP(8, 48)  STEP(9, 48)
    STEP(10, 48) STEP(11, 48) STEP(12, 48) STEP(13, 48) STEP(14, 48)
    STEP(15, 48) STEP(16, 48) STEP(17, 48) STEP(18, 48) STEP(19, 48)
    STEP(20, 48) STEP(21, 48) STEP(22, 48) STEP(23, 48)
    STEP(24, 32) STEP(25, 16) STEP(26, 0)
#undef STAGE
#undef STEP

    // epilogue: D layout col=lane&15, row=quad*4+reg; fused stats atomics
#pragma unroll
    for (int ct = 0; ct < 4; ++ct) {
        const int ch = ct * 16 + m;
        const float bv = bias[ch];
        float s = 0.f, q = 0.f;
#pragma unroll
        for (int mt = 0; mt < 4; ++mt) {
#pragma unroll
            for (int r = 0; r < 4; ++r) {
                const int vox = n0 + mt * 16 + quad * 4 + r;
                if (vox < N) {
                    const float v = acc[mt][ct][r] + bv;
                    out[(size_t)vox * NCH + ch] = v;
                    s += v;
                    q += v * v;
                }
            }
        }
        s += __shfl_xor(s, 16, 64);
        s += __shfl_xor(s, 32, 64);
        q += __shfl_xor(q, 16, 64);
        q += __shfl_xor(q, 32, 64);
        if (quad == 0) {
            atomicAdd(&stat[ch], s);
            atomicAdd(&stat[64 + ch], q);
        }
    }
}

// ---------------------------------------------------------------------------
// BN + ReLU, fp32 in -> bf16 out (conv2's gather input). 8 elems/thread.
// ---------------------------------------------------------------------------
__global__ __launch_bounds__(256)
void bn_relu_bf16_kernel(const float* __restrict__ x, const float* __restrict__ sums,
                         const float* __restrict__ gmm, const float* __restrict__ bet,
                         float invN, unsigned short* __restrict__ y, int total8)
{
    const int idx = blockIdx.x * 256 + threadIdx.x;
    if (idx >= total8) return;
    const int c0 = (idx & 7) * 8;
    const float4* xp = reinterpret_cast<const float4*>(x) + (size_t)idx * 2;
    const float4 a = xp[0], b = xp[1];
    float v[8] = {a.x, a.y, a.z, a.w, b.x, b.y, b.z, b.w};
    u16x8 o;
#pragma unroll
    for (int i = 0; i < 8; ++i) {
        const int c = c0 + i;
        const float mu  = sums[c] * invN;
        const float var = sums[64 + c] * invN - mu * mu;
        const float rs  = rsqrtf(var + EPSV);
        const float sc  = gmm[c] * rs;
        const float sh  = bet[c] - mu * sc;
        o[i] = f2bf(fmaxf(fmaf(v[i], sc, sh), 0.f));
    }
    reinterpret_cast<u16x8*>(y)[idx] = o;
}

// ---------------------------------------------------------------------------
// BN + residual + ReLU, in-place fp32 (final output)
// ---------------------------------------------------------------------------
__global__ __launch_bounds__(256)
void bn_res_relu_kernel(float* __restrict__ x, const float* __restrict__ feats,
                        const float* __restrict__ sums, const float* __restrict__ gmm,
                        const float* __restrict__ bet, float invN, int total4)
{
    const int idx = blockIdx.x * blockDim.x + threadIdx.x;
    if (idx >= total4) return;
    float4 v = reinterpret_cast<float4*>(x)[idx];
    const float4 f = reinterpret_cast<const float4*>(feats)[idx];
    const int c0 = (idx & 15) * 4;
    float sc[4], sh[4];
#pragma unroll
    for (int i = 0; i < 4; ++i) {
        const int c = c0 + i;
        const float mu  = sums[c] * invN;
        const float var = sums[64 + c] * invN - mu * mu;
        const float rs  = rsqrtf(var + EPSV);
        sc[i] = gmm[c] * rs;
        sh[i] = bet[c] - mu * sc[i];
    }
    v.x = fmaxf(fmaf(v.x, sc[0], sh[0]) + f.x, 0.f);
    v.y = fmaxf(fmaf(v.y, sc[1], sh[1]) + f.y, 0.f);
    v.z = fmaxf(fmaf(v.z, sc[2], sh[2]) + f.z, 0.f);
    v.w = fmaxf(fmaf(v.w, sc[3], sh[3]) + f.w, 0.f);
    reinterpret_cast<float4*>(x)[idx] = v;
}

extern "C" void kernel_launch(void* const* d_in, const int* in_sizes, int n_in,
                              void* d_out, int out_size, void* d_ws, size_t ws_size,
                              hipStream_t stream)
{
    const float* feats = (const float*)d_in[0];
    const int*   nbr   = (const int*)d_in[1];
    const float* W1    = (const float*)d_in[2];
    const float* b1    = (const float*)d_in[3];
    const float* g1    = (const float*)d_in[4];
    const float* be1   = (const float*)d_in[5];
    const float* W2    = (const float*)d_in[6];
    const float* b2    = (const float*)d_in[7];
    const float* g2    = (const float*)d_in[8];
    const float* be2   = (const float*)d_in[9];
    float* out = (float*)d_out;

    const int N  = in_sizes[0] / NCH;          // 100000
    const int NC = N * NCH;                    // 6,400,000
    const float invN = 1.0f / (float)N;

    // workspace layout
    float*          h0   = (float*)d_ws;                       // [N*C] fp32
    unsigned short* fbf  = (unsigned short*)(h0 + NC);         // [N*C] bf16
    unsigned short* hbf  = fbf + NC;                           // [N*C] bf16
    unsigned short* wt1  = hbf + NC;                           // 110592 bf16
    unsigned short* wt2  = wt1 + KOFF * 4096;                  // 110592 bf16
    float*          stat = (float*)(wt2 + KOFF * 4096);        // 256 fp32

    const int total8   = NC / 8;                               // 800000
    const int castGrid = (total8 + 255) / 256;                 // 3125
    const int prepGrid = 1 + 108 + castGrid;                   // 3234
    const int convGrid = (N + 63) / 64;                        // 1563

    prep_kernel<<<prepGrid, 256, 0, stream>>>(feats, W1, W2, fbf, wt1, wt2,
                                              stat, total8);
    conv_mfma_kernel<<<convGrid, 64, 0, stream>>>(fbf, nbr, wt1, b1, h0,
                                                  stat, N);
    bn_relu_bf16_kernel<<<castGrid, 256, 0, stream>>>(h0, stat, g1, be1, invN,
                                                      hbf, total8);
    conv_mfma_kernel<<<convGrid, 64, 0, stream>>>(hbf, nbr, wt2, b2, out,
                                                  stat + 128, N);
    bn_res_relu_kernel<<<(NC / 4 + 255) / 256, 256, 0, stream>>>(
        out, feats, stat + 128, g2, be2, invN, NC / 4);
}

// Round 7
// 366.353 us; speedup vs baseline: 1.0186x; 1.0186x over previous
//
#include <hip/hip_runtime.h>

#define NCH 64      // channels
#define KOFF 27     // kernel offsets
#define EPSV 1e-5f

typedef __attribute__((ext_vector_type(8))) short  bf16x8;
typedef __attribute__((ext_vector_type(4))) float  f32x4;
typedef __attribute__((ext_vector_type(8))) unsigned short u16x8;

__device__ __forceinline__ unsigned short f2bf(float x) {
    unsigned int u = __float_as_uint(x);
    u += 0x7fffu + ((u >> 16) & 1u);       // round-to-nearest-even
    return (unsigned short)(u >> 16);
}

// ---------------------------------------------------------------------------
// Fused prep: zero stats | W1->Wt1 | W2->Wt2 (B-fragment order) | feats->bf16
// Wt[(((k*2+s)*4+ct)*64+lane)*8 + j] = W[k][s*32+(lane>>4)*8+j][ct*16+(lane&15)]
// ---------------------------------------------------------------------------
__global__ __launch_bounds__(256)
void prep_kernel(const float* __restrict__ feats,
                 const float* __restrict__ W1, const float* __restrict__ W2,
                 unsigned short* __restrict__ fbf,
                 unsigned short* __restrict__ wt1, unsigned short* __restrict__ wt2,
                 float* __restrict__ stat, int total8)
{
    const int b = blockIdx.x;
    if (b == 0) {
        stat[threadIdx.x] = 0.f;           // 256 floats: stats1+stats2
        return;
    }
    if (b <= 108) {
        const float* W = (b <= 54) ? W1 : W2;
        unsigned short* Wt = (b <= 54) ? wt1 : wt2;
        const int t = (b <= 54 ? b - 1 : b - 55) * 256 + threadIdx.x; // 0..13823
        const int l  = t & 63;
        const int ct = (t >> 6) & 3;
        const int s  = (t >> 8) & 1;
        const int k  = t >> 9;
        const int d     = ct * 16 + (l & 15);
        const int cbase = s * 32 + (l >> 4) * 8;
        u16x8 o;
#pragma unroll
        for (int j = 0; j < 8; ++j)
            o[j] = f2bf(W[(size_t)k * 4096 + (size_t)(cbase + j) * 64 + d]);
        reinterpret_cast<u16x8*>(Wt)[t] = o;
        return;
    }
    const int idx = (b - 109) * 256 + threadIdx.x;
    if (idx >= total8) return;
    const float4* xp = reinterpret_cast<const float4*>(feats) + (size_t)idx * 2;
    const float4 a = xp[0], c = xp[1];
    u16x8 o;
    o[0] = f2bf(a.x); o[1] = f2bf(a.y); o[2] = f2bf(a.z); o[3] = f2bf(a.w);
    o[4] = f2bf(c.x); o[5] = f2bf(c.y); o[6] = f2bf(c.z); o[7] = f2bf(c.w);
    reinterpret_cast<u16x8*>(fbf)[idx] = o;
}

// ---------------------------------------------------------------------------
// Gathered conv via MFMA 16x16x32 bf16. 4-wave blocks; each wave independently
// owns 32 voxels x 64 ch, barrier-free. The 12 loads per k-step are VOLATILE
// INLINE-ASM global_load_dwordx4 (compiler cannot reorder/serialize them),
// depth-2 software pipeline with manual s_waitcnt vmcnt(12); the waitcnt asm
// carries the 12 destination fragments as "+v" operands so consumption cannot
// be hoisted above the wait. Fused per-channel stats via epilogue atomics.
// ---------------------------------------------------------------------------
template <typename OUT_T>
__global__ __launch_bounds__(256, 3)
void conv_mfma_kernel(const unsigned short* __restrict__ fin,
                      const int* __restrict__ nbr,
                      const unsigned short* __restrict__ Wt,
                      const float* __restrict__ bias,
                      OUT_T* __restrict__ out, float* __restrict__ stat, int N)
{
    __shared__ int s_idx[4 * 32 * KOFF];

    const int t    = threadIdx.x;
    const int lane = t & 63;
    const int w    = t >> 6;
    const int n0   = (blockIdx.x * 4 + w) * 32;
    const int m    = lane & 15;
    const int quad = lane >> 4;
    int* sw = s_idx + w * (32 * KOFF);

    {   // wave-private index stage, pre-scaled to byte offsets
        int rem = N - n0;
        rem = rem < 0 ? 0 : (rem > 32 ? 32 : rem);
        const int maxi = rem * KOFF;
        const int* nb  = nbr + (size_t)n0 * KOFF;
        for (int p = lane; p < 32 * KOFF; p += 64)
            sw[p] = ((p < maxi) ? nb[p] : 0) * (NCH * 2);
        // single-wave section: no barrier needed
    }

    const char* finB = (const char*)fin;
    const char* WtB  = (const char*)Wt;

    f32x4 acc[2][4];
#pragma unroll
    for (int mt = 0; mt < 2; ++mt)
#pragma unroll
        for (int ct = 0; ct < 4; ++ct) acc[mt][ct] = (f32x4){0.f, 0.f, 0.f, 0.f};

    bf16x8 A[2][2][2];   // [buf][m-tile][s]
    bf16x8 B[2][2][4];   // [buf][s][ct]

#define LOADK(kk, p)                                                          \
    {                                                                         \
        const char* fp0 = finB + sw[(0 * 16 + m) * KOFF + (kk)] + quad * 16;  \
        const char* fp1 = finB + sw[(1 * 16 + m) * KOFF + (kk)] + quad * 16;  \
        asm volatile("global_load_dwordx4 %0, %1, off"                        \
                     : "=v"(A[p][0][0]) : "v"(fp0));                          \
        asm volatile("global_load_dwordx4 %0, %1, off offset:64"              \
                     : "=v"(A[p][0][1]) : "v"(fp0));                          \
        asm volatile("global_load_dwordx4 %0, %1, off"                        \
                     : "=v"(A[p][1][0]) : "v"(fp1));                          \
        asm volatile("global_load_dwordx4 %0, %1, off offset:64"              \
                     : "=v"(A[p][1][1]) : "v"(fp1));                          \
        const char* wp = WtB + (kk)*8192 + lane * 16;                         \
        asm volatile("global_load_dwordx4 %0, %1, off"                        \
                     : "=v"(B[p][0][0]) : "v"(wp));                           \
        asm volatile("global_load_dwordx4 %0, %1, off offset:1024"            \
                     : "=v"(B[p][0][1]) : "v"(wp));                           \
        asm volatile("global_load_dwordx4 %0, %1, off offset:2048"            \
                     : "=v"(B[p][0][2]) : "v"(wp));                           \
        asm volatile("global_load_dwordx4 %0, %1, off offset:3072"            \
                     : "=v"(B[p][0][3]) : "v"(wp));                           \
        const char* wq = wp + 4096;                                           \
        asm volatile("global_load_dwordx4 %0, %1, off"                        \
                     : "=v"(B[p][1][0]) : "v"(wq));                           \
        asm volatile("global_load_dwordx4 %0, %1, off offset:1024"            \
                     : "=v"(B[p][1][1]) : "v"(wq));                           \
        asm volatile("global_load_dwordx4 %0, %1, off offset:2048"            \
                     : "=v"(B[p][1][2]) : "v"(wq));                           \
        asm volatile("global_load_dwordx4 %0, %1, off offset:3072"            \
                     : "=v"(B[p][1][3]) : "v"(wq));                           \
    }

#define WAITDEP(p, VMSTR)                                                     \
    asm volatile("s_waitcnt vmcnt(" VMSTR ")"                                 \
                 : "+v"(A[p][0][0]), "+v"(A[p][0][1]),                        \
                   "+v"(A[p][1][0]), "+v"(A[p][1][1]),                        \
                   "+v"(B[p][0][0]), "+v"(B[p][0][1]),                        \
                   "+v"(B[p][0][2]), "+v"(B[p][0][3]),                        \
                   "+v"(B[p][1][0]), "+v"(B[p][1][1]),                        \
                   "+v"(B[p][1][2]), "+v"(B[p][1][3]) :: "memory");

#define DOMFMA(p)                                                             \
    {                                                                         \
        _Pragma("unroll")                                                     \
        for (int mt = 0; mt < 2; ++mt)                                        \
            _Pragma("unroll")                                                 \
            for (int sf = 0; sf < 2; ++sf)                                    \
                _Pragma("unroll")                                             \
                for (int ct = 0; ct < 4; ++ct)                                \
                    acc[mt][ct] = __builtin_amdgcn_mfma_f32_16x16x32_bf16(    \
                        A[p][mt][sf], B[p][sf][ct], acc[mt][ct], 0, 0, 0);    \
    }

#define STEPK(kk)                                                             \
    WAITDEP((kk) & 1, "12") DOMFMA((kk) & 1) LOADK((kk) + 2, (kk) & 1)

    LOADK(0, 0) LOADK(1, 1)
    STEPK(0)  STEPK(1)  STEPK(2)  STEPK(3)  STEPK(4)
    STEPK(5)  STEPK(6)  STEPK(7)  STEPK(8)  STEPK(9)
    STEPK(10) STEPK(11) STEPK(12) STEPK(13) STEPK(14)
    STEPK(15) STEPK(16) STEPK(17) STEPK(18) STEPK(19)
    STEPK(20) STEPK(21) STEPK(22) STEPK(23) STEPK(24)
    WAITDEP(1, "12") DOMFMA(1)      // k = 25
    WAITDEP(0, "0")  DOMFMA(0)      // k = 26
#undef LOADK
#undef WAITDEP
#undef DOMFMA
#undef STEPK

    // epilogue: D layout col=lane&15, row=quad*4+reg; fused stats atomics
#pragma unroll
    for (int ct = 0; ct < 4; ++ct) {
        const int ch = ct * 16 + m;
        const float bv = bias[ch];
        float s = 0.f, q = 0.f;
#pragma unroll
        for (int mt = 0; mt < 2; ++mt) {
#pragma unroll
            for (int r = 0; r < 4; ++r) {
                const int vox = n0 + mt * 16 + quad * 4 + r;
                if (vox < N) {
                    const float v = acc[mt][ct][r] + bv;
                    if constexpr (__is_same(OUT_T, unsigned short))
                        out[(size_t)vox * NCH + ch] = f2bf(v);
                    else
                        out[(size_t)vox * NCH + ch] = v;
                    s += v;
                    q += v * v;
                }
            }
        }
        s += __shfl_xor(s, 16, 64);
        s += __shfl_xor(s, 32, 64);
        q += __shfl_xor(q, 16, 64);
        q += __shfl_xor(q, 32, 64);
        if (quad == 0) {
            atomicAdd(&stat[ch], s);
            atomicAdd(&stat[64 + ch], q);
        }
    }
}

// ---------------------------------------------------------------------------
// BN + ReLU, bf16 in -> bf16 out (conv2's gather input). 8 elems/thread.
// ---------------------------------------------------------------------------
__global__ __launch_bounds__(256)
void bn_relu_bf16_kernel(const unsigned short* __restrict__ x,
                         const float* __restrict__ sums,
                         const float* __restrict__ gmm, const float* __restrict__ bet,
                         float invN, unsigned short* __restrict__ y, int total8)
{
    const int idx = blockIdx.x * 256 + threadIdx.x;
    if (idx >= total8) return;
    const int c0 = (idx & 7) * 8;
    const u16x8 a = reinterpret_cast<const u16x8*>(x)[idx];
    u16x8 o;
#pragma unroll
    for (int i = 0; i < 8; ++i) {
        const int c = c0 + i;
        const float mu  = sums[c] * invN;
        const float var = sums[64 + c] * invN - mu * mu;
        const float rs  = rsqrtf(var + EPSV);
        const float sc  = gmm[c] * rs;
        const float sh  = bet[c] - mu * sc;
        const float v   = __uint_as_float((unsigned)a[i] << 16);
        o[i] = f2bf(fmaxf(fmaf(v, sc, sh), 0.f));
    }
    reinterpret_cast<u16x8*>(y)[idx] = o;
}

// ---------------------------------------------------------------------------
// BN + residual + ReLU, in-place fp32 (final output)
// ---------------------------------------------------------------------------
__global__ __launch_bounds__(256)
void bn_res_relu_kernel(float* __restrict__ x, const float* __restrict__ feats,
                        const float* __restrict__ sums, const float* __restrict__ gmm,
                        const float* __restrict__ bet, float invN, int total4)
{
    const int idx = blockIdx.x * blockDim.x + threadIdx.x;
    if (idx >= total4) return;
    float4 v = reinterpret_cast<float4*>(x)[idx];
    const float4 f = reinterpret_cast<const float4*>(feats)[idx];
    const int c0 = (idx & 15) * 4;
    float sc[4], sh[4];
#pragma unroll
    for (int i = 0; i < 4; ++i) {
        const int c = c0 + i;
        const float mu  = sums[c] * invN;
        const float var = sums[64 + c] * invN - mu * mu;
        const float rs  = rsqrtf(var + EPSV);
        sc[i] = gmm[c] * rs;
        sh[i] = bet[c] - mu * sc[i];
    }
    v.x = fmaxf(fmaf(v.x, sc[0], sh[0]) + f.x, 0.f);
    v.y = fmaxf(fmaf(v.y, sc[1], sh[1]) + f.y, 0.f);
    v.z = fmaxf(fmaf(v.z, sc[2], sh[2]) + f.z, 0.f);
    v.w = fmaxf(fmaf(v.w, sc[3], sh[3]) + f.w, 0.f);
    reinterpret_cast<float4*>(x)[idx] = v;
}

extern "C" void kernel_launch(void* const* d_in, const int* in_sizes, int n_in,
                              void* d_out, int out_size, void* d_ws, size_t ws_size,
                              hipStream_t stream)
{
    const float* feats = (const float*)d_in[0];
    const int*   nbr   = (const int*)d_in[1];
    const float* W1    = (const float*)d_in[2];
    const float* b1    = (const float*)d_in[3];
    const float* g1    = (const float*)d_in[4];
    const float* be1   = (const float*)d_in[5];
    const float* W2    = (const float*)d_in[6];
    const float* b2    = (const float*)d_in[7];
    const float* g2    = (const float*)d_in[8];
    const float* be2   = (const float*)d_in[9];
    float* out = (float*)d_out;

    const int N  = in_sizes[0] / NCH;          // 100000
    const int NC = N * NCH;                    // 6,400,000
    const float invN = 1.0f / (float)N;

    // workspace layout (all bf16 intermediates)
    unsigned short* fbf  = (unsigned short*)d_ws;              // [N*C] bf16
    unsigned short* hpre = fbf + NC;                           // [N*C] bf16
    unsigned short* hbf  = hpre + NC;                          // [N*C] bf16
    unsigned short* wt1  = hbf + NC;                           // 110592 bf16
    unsigned short* wt2  = wt1 + KOFF * 4096;                  // 110592 bf16
    float*          stat = (float*)(wt2 + KOFF * 4096);        // 256 fp32

    const int total8   = NC / 8;                               // 800000
    const int castGrid = (total8 + 255) / 256;                 // 3125
    const int prepGrid = 1 + 108 + castGrid;                   // 3234
    const int convGrid = (N + 127) / 128;                      // 782

    prep_kernel<<<prepGrid, 256, 0, stream>>>(feats, W1, W2, fbf, wt1, wt2,
                                              stat, total8);
    conv_mfma_kernel<unsigned short><<<convGrid, 256, 0, stream>>>(
        fbf, nbr, wt1, b1, hpre, stat, N);
    bn_relu_bf16_kernel<<<castGrid, 256, 0, stream>>>(hpre, stat, g1, be1, invN,
                                                      hbf, total8);
    conv_mfma_kernel<float><<<convGrid, 256, 0, stream>>>(
        hbf, nbr, wt2, b2, out, stat + 128, N);
    bn_res_relu_kernel<<<(NC / 4 + 255) / 256, 256, 0, stream>>>(
        out, feats, stat + 128, g2, be2, invN, NC / 4);
}